// Round 1
// baseline (743.244 us; speedup 1.0000x reference)
//
#include <hip/hip_runtime.h>
#include <hip/hip_bf16.h>
#include <math.h>

#define MTOK 16384   // B*N = 4*4096

typedef __attribute__((ext_vector_type(8))) short bf16x8;
typedef __attribute__((ext_vector_type(4))) float f32x4;

__device__ __forceinline__ float bf2f(ushort u) {
  union { unsigned int u; float f; } c; c.u = ((unsigned int)u) << 16; return c.f;
}
__device__ __forceinline__ ushort f2bf(float f) {
  union { float f; unsigned int u; } c; c.f = f;
  unsigned int r = c.u + 0x7fffu + ((c.u >> 16) & 1u);
  return (ushort)(r >> 16);
}

__device__ __forceinline__ void gload_lds16(const void* g, void* l) {
  __builtin_amdgcn_global_load_lds(
      (const __attribute__((address_space(1))) unsigned int*)g,
      (__attribute__((address_space(3))) unsigned int*)l, 16, 0, 0);
}

// ---------------- fp32 -> bf16 convert (weights) ----------------
__global__ __launch_bounds__(256)
void f32_to_bf16_k(const float* __restrict__ in, ushort* __restrict__ out, int n4) {
  int i = blockIdx.x * 256 + threadIdx.x;
  if (i >= n4) return;
  float4 v = *(const float4*)&in[(size_t)i * 4];
  ushort4 o;
  o.x = f2bf(v.x); o.y = f2bf(v.y); o.z = f2bf(v.z); o.w = f2bf(v.w);
  *(ushort4*)&out[(size_t)i * 4] = o;
}

// ---------------- RMSNorm: fp32 in -> bf16 out ----------------
// y = x * scale * (sqrt(1024)+eps)/||x||
__global__ __launch_bounds__(256)
void rmsnorm_k(const float* __restrict__ x, const float* __restrict__ scale,
               ushort* __restrict__ out) {
  __shared__ float red[4];
  int row = blockIdx.x;
  int t = threadIdx.x;
  const float* xr = x + (size_t)row * 1024;
  float4 v = *(const float4*)&xr[t * 4];
  float s = v.x*v.x + v.y*v.y + v.z*v.z + v.w*v.w;
  #pragma unroll
  for (int off = 32; off > 0; off >>= 1) s += __shfl_xor(s, off);
  if ((t & 63) == 0) red[t >> 6] = s;
  __syncthreads();
  float tot = red[0] + red[1] + red[2] + red[3];
  float rn = (32.0f + 1e-6f) / sqrtf(tot);
  float4 sc = *(const float4*)&scale[t * 4];
  ushort4 o;
  o.x = f2bf(v.x * rn * sc.x);
  o.y = f2bf(v.y * rn * sc.y);
  o.z = f2bf(v.z * rn * sc.z);
  o.w = f2bf(v.w * rn * sc.w);
  *(ushort4*)&out[(size_t)row * 1024 + t * 4] = o;
}

// ---------------- bf16 MFMA GEMM: out[M,F] = A[M,K] @ W[F,K]^T ----------------
// 128x128 tile, BK=32, 4 waves (2x2), each wave 64x64 = 4x4 frags of 16x16x32.
// LDS lane-linear (global_load_lds), kc-chunk XOR swizzle applied on the global
// SOURCE address and on the READ address (both-sides, rule #21).
// EPI: 0 = qkv (phi on cols<2048, bf16 out)
//      1 = residual: outf32 = resid + gamma*(acc+bias)
//      2 = gelu(acc+bias), bf16 out
template<int EPI>
__global__ __launch_bounds__(256, 2)
void gemm_bt(const ushort* __restrict__ A, const ushort* __restrict__ W,
             void* __restrict__ outp, const float* __restrict__ bias,
             const float* __restrict__ gamma, const float* __restrict__ resid,
             int M, int F, int K) {
  __shared__ ushort lA[128 * 32];
  __shared__ ushort lB[128 * 32];
  const int tid = threadIdx.x;
  const int lane = tid & 63;
  const int w = tid >> 6;
  const int nBn = F >> 7;
  const int bm = blockIdx.x / nBn;
  const int bn = blockIdx.x % nBn;
  const int brow = bm << 7, bcol = bn << 7;
  const int wr = w >> 1, wc = w & 1;

  // staging: wave w covers tile rows [w*16, w*16+16) (inst0) and +64 (inst1),
  // lane -> row = w*16 + lane/4, kc_pos = lane&3. LDS dst is lane-linear.
  const int srow = (w << 4) + (lane >> 2);
  const int key = (srow >> 1) & 3;            // same key for srow and srow+64
  const int kcsrc = (lane & 3) ^ key;
  const ushort* gA0 = A + (size_t)(brow + srow) * K + kcsrc * 8;
  const ushort* gA1 = gA0 + (size_t)64 * K;
  const ushort* gB0 = W + (size_t)(bcol + srow) * K + kcsrc * 8;
  const ushort* gB1 = gB0 + (size_t)64 * K;
  ushort* lA0 = &lA[w * 512];
  ushort* lA1 = &lA[2048 + w * 512];
  ushort* lB0 = &lB[w * 512];
  ushort* lB1 = &lB[2048 + w * 512];

  const int frow = lane & 15;
  const int kq = lane >> 4;

  f32x4 acc[4][4];
  #pragma unroll
  for (int i = 0; i < 4; ++i)
    #pragma unroll
    for (int j = 0; j < 4; ++j) acc[i][j] = (f32x4){0.f, 0.f, 0.f, 0.f};

  for (int k0 = 0; k0 < K; k0 += 32) {
    gload_lds16(gA0 + k0, lA0);
    gload_lds16(gA1 + k0, lA1);
    gload_lds16(gB0 + k0, lB0);
    gload_lds16(gB1 + k0, lB1);
    __syncthreads();   // compiler drains vmcnt before s_barrier

    bf16x8 af[4], bfr[4];
    #pragma unroll
    for (int mi = 0; mi < 4; ++mi) {
      int row = (wr << 6) + (mi << 4) + frow;
      int off = (row << 5) + ((kq ^ ((row >> 1) & 3)) << 3);
      af[mi] = *(const bf16x8*)&lA[off];
    }
    #pragma unroll
    for (int ni = 0; ni < 4; ++ni) {
      int row = (wc << 6) + (ni << 4) + frow;
      int off = (row << 5) + ((kq ^ ((row >> 1) & 3)) << 3);
      bfr[ni] = *(const bf16x8*)&lB[off];
    }
    #pragma unroll
    for (int mi = 0; mi < 4; ++mi)
      #pragma unroll
      for (int ni = 0; ni < 4; ++ni)
        acc[mi][ni] = __builtin_amdgcn_mfma_f32_16x16x32_bf16(
            af[mi], bfr[ni], acc[mi][ni], 0, 0, 0);
    __syncthreads();
  }

  // epilogue: C row = (lane>>4)*4+r, col = lane&15 (m89-verified layout)
  #pragma unroll
  for (int mi = 0; mi < 4; ++mi) {
    #pragma unroll
    for (int ni = 0; ni < 4; ++ni) {
      int col = bcol + (wc << 6) + (ni << 4) + frow;
      int rbase = brow + (wr << 6) + (mi << 4) + (kq << 2);
      #pragma unroll
      for (int r = 0; r < 4; ++r) {
        int row = rbase + r;
        float v = acc[mi][ni][r];
        size_t idx = (size_t)row * F + col;
        if (EPI == 0) {
          if (col < 2048) v = __expf(-0.5f * v * v);   // phi on q,k
          ((ushort*)outp)[idx] = f2bf(v);
        } else if (EPI == 1) {
          ((float*)outp)[idx] = resid[idx] + gamma[col] * (v + bias[col]);
        } else {
          float t2 = v + bias[col];
          ((ushort*)outp)[idx] =
              f2bf(0.5f * t2 * (1.0f + erff(t2 * 0.70710678118f)));
        }
      }
    }
  }
}

// ---------------- attention: kv[b,h,d,e] += k[n,d]*v[n,e]; ksum[b,h,d] ----------------
// grid 512 = b(4) x h(16) x s(8), each block reduces 512 tokens, atomicAdd out.
__global__ __launch_bounds__(256)
void attn_kv_k(const ushort* __restrict__ qkvp, float* __restrict__ kv,
               float* __restrict__ ksum) {
  int bi = blockIdx.x;
  int s = bi & 7, h = (bi >> 3) & 15, b = bi >> 7;
  int t = threadIdx.x;
  int d1 = t >> 2, jb = (t & 3) * 16;
  __shared__ ushort sk[64 * 72];
  __shared__ ushort sv[64 * 72];
  float acc[16] = {};
  float ks = 0.f;
  for (int c = 0; c < 8; ++c) {
    __syncthreads();
    int n0 = s * 512 + c * 64;
    for (int i = t; i < 512; i += 256) {
      int tok = i >> 3, seg = i & 7;
      size_t base = ((size_t)(b * 4096 + n0 + tok)) * 3072 + h * 64 + seg * 8;
      *(uint4*)&sk[tok * 72 + seg * 8] = *(const uint4*)&qkvp[base + 1024];
      *(uint4*)&sv[tok * 72 + seg * 8] = *(const uint4*)&qkvp[base + 2048];
    }
    __syncthreads();
    for (int n = 0; n < 64; ++n) {
      float kd = bf2f(sk[n * 72 + d1]);
      ks += kd;
      union { uint4 q[2]; ushort u[16]; } vv;
      vv.q[0] = *(const uint4*)&sv[n * 72 + jb];
      vv.q[1] = *(const uint4*)&sv[n * 72 + jb + 8];
      #pragma unroll
      for (int j = 0; j < 16; ++j) acc[j] += kd * bf2f(vv.u[j]);
    }
  }
  size_t kb = ((size_t)(b * 16 + h)) * 4096 + d1 * 64 + jb;
  #pragma unroll
  for (int j = 0; j < 16; ++j) atomicAdd(&kv[kb + j], acc[j]);
  if ((t & 3) == 0) atomicAdd(&ksum[(b * 16 + h) * 64 + d1], ks);
}

// ---------------- attention: out[n,e] = z * sum_d q[n,d]*kv[d,e] ----------------
// grid 256 = b(4) x 64-token-chunk(64); loop h staging kv[b,h] (16KB) in LDS.
__global__ __launch_bounds__(256)
void attn_out_k(const ushort* __restrict__ qkvp, const float* __restrict__ kv,
                const float* __restrict__ ksum, ushort* __restrict__ attn_o) {
  int b = blockIdx.x >> 6;
  int chunk = blockIdx.x & 63;
  int t = threadIdx.x;
  int tt = t >> 2;
  int jb = (t & 3) * 16;
  int m = b * 4096 + chunk * 64 + tt;
  __shared__ float skv[64 * 64];
  __shared__ ushort sq[64 * 72];
  __shared__ float sks[64];
  for (int h = 0; h < 16; ++h) {
    __syncthreads();
    const float* kvh = kv + ((size_t)(b * 16 + h)) * 4096;
    for (int i = t; i < 1024; i += 256)
      ((float4*)skv)[i] = ((const float4*)kvh)[i];
    for (int i = t; i < 512; i += 256) {
      int tok = i >> 3, seg = i & 7;
      *(uint4*)&sq[tok * 72 + seg * 8] =
          *(const uint4*)&qkvp[((size_t)(b * 4096 + chunk * 64 + tok)) * 3072 +
                               h * 64 + seg * 8];
    }
    if (t < 64) sks[t] = ksum[(b * 16 + h) * 64 + t];
    __syncthreads();
    float acc[16] = {};
    float dot = 0.f;
    for (int d = 0; d < 64; ++d) {
      float qd = bf2f(sq[tt * 72 + d]);
      dot += qd * sks[d];
      const float4* kr = (const float4*)&skv[d * 64 + jb];
      float4 k0 = kr[0], k1 = kr[1], k2 = kr[2], k3 = kr[3];
      acc[0] += qd * k0.x;  acc[1] += qd * k0.y;
      acc[2] += qd * k0.z;  acc[3] += qd * k0.w;
      acc[4] += qd * k1.x;  acc[5] += qd * k1.y;
      acc[6] += qd * k1.z;  acc[7] += qd * k1.w;
      acc[8] += qd * k2.x;  acc[9] += qd * k2.y;
      acc[10] += qd * k2.z; acc[11] += qd * k2.w;
      acc[12] += qd * k3.x; acc[13] += qd * k3.y;
      acc[14] += qd * k3.z; acc[15] += qd * k3.w;
    }
    float z = 1.0f / (dot + 1e-6f);
    union { uint4 q[2]; ushort u[16]; } ou;
    #pragma unroll
    for (int j = 0; j < 16; ++j) ou.u[j] = f2bf(acc[j] * z);
    size_t ob = (size_t)m * 1024 + h * 64 + jb;
    *(uint4*)&attn_o[ob] = ou.q[0];
    *(uint4*)&attn_o[ob + 8] = ou.q[1];
    __syncthreads();
  }
}

extern "C" void kernel_launch(void* const* d_in, const int* in_sizes, int n_in,
                              void* d_out, int out_size, void* d_ws, size_t ws_size,
                              hipStream_t stream) {
  const float* x       = (const float*)d_in[0];
  const float* scale1  = (const float*)d_in[1];
  const float* scale2  = (const float*)d_in[2];
  const float* gamma   = (const float*)d_in[3];
  const float* qkv_w   = (const float*)d_in[4];
  const float* proj_w  = (const float*)d_in[5];
  const float* proj_b  = (const float*)d_in[6];
  const float* conv1_w = (const float*)d_in[7];
  const float* conv1_b = (const float*)d_in[8];
  const float* conv2_w = (const float*)d_in[9];
  const float* conv2_b = (const float*)d_in[10];
  float* out = (float*)d_out;

  char* ws = (char*)d_ws;
  size_t off = 0;
  auto alloc = [&](size_t bytes) {
    void* p = ws + off;
    off += (bytes + 255) & ~(size_t)255;
    return p;
  };
  ushort* xn     = (ushort*)alloc((size_t)MTOK * 1024 * 2);
  ushort* qkvp   = (ushort*)alloc((size_t)MTOK * 3072 * 2);  // later reused as MLP hidden
  ushort* attn_o = (ushort*)alloc((size_t)MTOK * 1024 * 2);
  float*  kv     = (float*)alloc((size_t)(4 * 16 * 64 * 64 + 4 * 16 * 64) * 4);
  float*  ksum   = kv + 4 * 16 * 64 * 64;
  ushort* wq = (ushort*)alloc((size_t)3072 * 1024 * 2);
  ushort* wp = (ushort*)alloc((size_t)1024 * 1024 * 2);
  ushort* w1 = (ushort*)alloc((size_t)2048 * 1024 * 2);
  ushort* w2 = (ushort*)alloc((size_t)1024 * 2048 * 2);
  if (off > ws_size) return;  // ws too small -> clean validation failure

  hipMemsetAsync(kv, 0, (size_t)(4 * 16 * 64 * 64 + 4 * 16 * 64) * 4, stream);
  f32_to_bf16_k<<<3072, 256, 0, stream>>>(qkv_w, wq, 786432);
  f32_to_bf16_k<<<1024, 256, 0, stream>>>(proj_w, wp, 262144);
  f32_to_bf16_k<<<2048, 256, 0, stream>>>(conv1_w, w1, 524288);
  f32_to_bf16_k<<<2048, 256, 0, stream>>>(conv2_w, w2, 524288);

  // attention branch
  rmsnorm_k<<<MTOK, 256, 0, stream>>>(x, scale1, xn);
  gemm_bt<0><<<128 * 24, 256, 0, stream>>>(xn, wq, qkvp, nullptr, nullptr, nullptr,
                                           MTOK, 3072, 1024);
  attn_kv_k<<<512, 256, 0, stream>>>(qkvp, kv, ksum);
  attn_out_k<<<256, 256, 0, stream>>>(qkvp, kv, ksum, attn_o);
  gemm_bt<1><<<128 * 8, 256, 0, stream>>>(attn_o, wp, out, proj_b, gamma, x,
                                          MTOK, 1024, 1024);   // out = x1 (fp32)

  // MLP branch (x1 lives in d_out; conv2 epilogue reads+rewrites it)
  rmsnorm_k<<<MTOK, 256, 0, stream>>>(out, scale2, xn);
  gemm_bt<2><<<128 * 16, 256, 0, stream>>>(xn, w1, qkvp, conv1_b, nullptr, nullptr,
                                           MTOK, 2048, 1024);
  gemm_bt<1><<<128 * 8, 256, 0, stream>>>(qkvp, w2, out, conv2_b, gamma, out,
                                          MTOK, 1024, 2048);
}

// Round 2
// 503.631 us; speedup vs baseline: 1.4758x; 1.4758x over previous
//
#include <hip/hip_runtime.h>
#include <hip/hip_bf16.h>
#include <math.h>

#define MTOK 16384   // B*N = 4*4096

typedef __attribute__((ext_vector_type(8))) short bf16x8;
typedef __attribute__((ext_vector_type(4))) float f32x4;

__device__ __forceinline__ float bf2f(ushort u) {
  union { unsigned int u; float f; } c; c.u = ((unsigned int)u) << 16; return c.f;
}
__device__ __forceinline__ ushort f2bf(float f) {
  union { float f; unsigned int u; } c; c.f = f;
  unsigned int r = c.u + 0x7fffu + ((c.u >> 16) & 1u);
  return (ushort)(r >> 16);
}

__device__ __forceinline__ void gload_lds16(const void* g, void* l) {
  __builtin_amdgcn_global_load_lds(
      (const __attribute__((address_space(1))) unsigned int*)g,
      (__attribute__((address_space(3))) unsigned int*)l, 16, 0, 0);
}

// ---------------- fp32 -> bf16 convert (weights) ----------------
__global__ __launch_bounds__(256)
void f32_to_bf16_k(const float* __restrict__ in, ushort* __restrict__ out, int n4) {
  int i = blockIdx.x * 256 + threadIdx.x;
  if (i >= n4) return;
  float4 v = *(const float4*)&in[(size_t)i * 4];
  ushort4 o;
  o.x = f2bf(v.x); o.y = f2bf(v.y); o.z = f2bf(v.z); o.w = f2bf(v.w);
  *(ushort4*)&out[(size_t)i * 4] = o;
}

// ---------------- RMSNorm: fp32 in -> bf16 out ----------------
__global__ __launch_bounds__(256)
void rmsnorm_k(const float* __restrict__ x, const float* __restrict__ scale,
               ushort* __restrict__ out) {
  __shared__ float red[4];
  int row = blockIdx.x;
  int t = threadIdx.x;
  const float* xr = x + (size_t)row * 1024;
  float4 v = *(const float4*)&xr[t * 4];
  float s = v.x*v.x + v.y*v.y + v.z*v.z + v.w*v.w;
  #pragma unroll
  for (int off = 32; off > 0; off >>= 1) s += __shfl_xor(s, off);
  if ((t & 63) == 0) red[t >> 6] = s;
  __syncthreads();
  float tot = red[0] + red[1] + red[2] + red[3];
  float rn = (32.0f + 1e-6f) / sqrtf(tot);
  float4 sc = *(const float4*)&scale[t * 4];
  ushort4 o;
  o.x = f2bf(v.x * rn * sc.x);
  o.y = f2bf(v.y * rn * sc.y);
  o.z = f2bf(v.z * rn * sc.z);
  o.w = f2bf(v.w * rn * sc.w);
  *(ushort4*)&out[(size_t)row * 1024 + t * 4] = o;
}

// ---------------- bf16 MFMA GEMM: out[M,F] = A[M,K] @ W[F,K]^T ----------------
// EPI 0: qkv — q (phi) token-major to outp; k (phi) / v transposed [b,h,ch,n] to kTp/vTp
// EPI 1: residual: outf32 = resid + gamma*(acc+bias)
// EPI 2: gelu(acc+bias), bf16 out
template<int EPI>
__global__ __launch_bounds__(256, 2)
void gemm_bt(const ushort* __restrict__ A, const ushort* __restrict__ W,
             void* __restrict__ outp, const float* __restrict__ bias,
             const float* __restrict__ gamma, const float* __restrict__ resid,
             ushort* __restrict__ kTp, ushort* __restrict__ vTp,
             int M, int F, int K) {
  __shared__ ushort lA[128 * 32];
  __shared__ ushort lB[128 * 32];
  const int tid = threadIdx.x;
  const int lane = tid & 63;
  const int w = tid >> 6;
  const int nBn = F >> 7;
  const int bm = blockIdx.x / nBn;
  const int bn = blockIdx.x % nBn;
  const int brow = bm << 7, bcol = bn << 7;
  const int wr = w >> 1, wc = w & 1;

  const int srow = (w << 4) + (lane >> 2);
  const int key = (srow >> 1) & 3;
  const int kcsrc = (lane & 3) ^ key;
  const ushort* gA0 = A + (size_t)(brow + srow) * K + kcsrc * 8;
  const ushort* gA1 = gA0 + (size_t)64 * K;
  const ushort* gB0 = W + (size_t)(bcol + srow) * K + kcsrc * 8;
  const ushort* gB1 = gB0 + (size_t)64 * K;
  ushort* lA0 = &lA[w * 512];
  ushort* lA1 = &lA[2048 + w * 512];
  ushort* lB0 = &lB[w * 512];
  ushort* lB1 = &lB[2048 + w * 512];

  const int frow = lane & 15;
  const int kq = lane >> 4;

  f32x4 acc[4][4];
  #pragma unroll
  for (int i = 0; i < 4; ++i)
    #pragma unroll
    for (int j = 0; j < 4; ++j) acc[i][j] = (f32x4){0.f, 0.f, 0.f, 0.f};

  for (int k0 = 0; k0 < K; k0 += 32) {
    gload_lds16(gA0 + k0, lA0);
    gload_lds16(gA1 + k0, lA1);
    gload_lds16(gB0 + k0, lB0);
    gload_lds16(gB1 + k0, lB1);
    __syncthreads();

    bf16x8 af[4], bfr[4];
    #pragma unroll
    for (int mi = 0; mi < 4; ++mi) {
      int row = (wr << 6) + (mi << 4) + frow;
      int off = (row << 5) + ((kq ^ ((row >> 1) & 3)) << 3);
      af[mi] = *(const bf16x8*)&lA[off];
    }
    #pragma unroll
    for (int ni = 0; ni < 4; ++ni) {
      int row = (wc << 6) + (ni << 4) + frow;
      int off = (row << 5) + ((kq ^ ((row >> 1) & 3)) << 3);
      bfr[ni] = *(const bf16x8*)&lB[off];
    }
    #pragma unroll
    for (int mi = 0; mi < 4; ++mi)
      #pragma unroll
      for (int ni = 0; ni < 4; ++ni)
        acc[mi][ni] = __builtin_amdgcn_mfma_f32_16x16x32_bf16(
            af[mi], bfr[ni], acc[mi][ni], 0, 0, 0);
    __syncthreads();
  }

  #pragma unroll
  for (int mi = 0; mi < 4; ++mi) {
    #pragma unroll
    for (int ni = 0; ni < 4; ++ni) {
      int col = bcol + (wc << 6) + (ni << 4) + frow;
      int rbase = brow + (wr << 6) + (mi << 4) + (kq << 2);
      if (EPI == 0) {
        if (col < 1024) {
          // q: phi, token-major
          #pragma unroll
          for (int r = 0; r < 4; ++r) {
            float v = acc[mi][ni][r];
            ((ushort*)outp)[(size_t)(rbase + r) * 1024 + col] =
                f2bf(__expf(-0.5f * v * v));
          }
        } else {
          // k (phi) or v: transposed [b,h,ch,n]; 4 consecutive tokens -> ushort4
          bool isk = col < 2048;
          int c = col - (isk ? 1024 : 2048);
          int b = rbase >> 12, n = rbase & 4095;
          ushort4 o;
          #pragma unroll
          for (int r = 0; r < 4; ++r) {
            float v = acc[mi][ni][r];
            if (isk) v = __expf(-0.5f * v * v);
            ((ushort*)&o)[r] = f2bf(v);
          }
          ushort* dst = (isk ? kTp : vTp) +
                        ((size_t)(b * 16 + (c >> 6)) * 64 + (c & 63)) * 4096 + n;
          *(ushort4*)dst = o;
        }
      } else {
        #pragma unroll
        for (int r = 0; r < 4; ++r) {
          int row = rbase + r;
          float v = acc[mi][ni][r];
          size_t idx = (size_t)row * F + col;
          if (EPI == 1) {
            ((float*)outp)[idx] = resid[idx] + gamma[col] * (v + bias[col]);
          } else {
            float t2 = v + bias[col];
            ((ushort*)outp)[idx] =
                f2bf(0.5f * t2 * (1.0f + erff(t2 * 0.70710678118f)));
          }
        }
      }
    }
  }
}

// ---------------- kvT[b,h,e,d] = sum_n v[n,e]*k[n,d]  (MFMA, split-K) ----------------
// grid 512 = b(4) x h(16) x kslice(8); 4 waves each take 128 tokens of the slice.
// A-frags from vT rows (e), B-frags from kT rows (d), direct global loads.
// ksum[b,h,d] folded in from B-fragments.
__global__ __launch_bounds__(256)
void attn_kv_mfma(const ushort* __restrict__ kT, const ushort* __restrict__ vT,
                  float* __restrict__ kvT, float* __restrict__ ksum) {
  __shared__ float red[4][4096];
  int bi = blockIdx.x;
  int ksl = bi & 7, h = (bi >> 3) & 15, b = bi >> 7;
  int tid = threadIdx.x, lane = tid & 63, w = tid >> 6;
  int frow = lane & 15, kq = lane >> 4;
  const size_t bh = (size_t)(b * 16 + h) * 64;
  const ushort* vb = vT + bh * 4096;
  const ushort* kb = kT + bh * 4096;
  int tk0 = ksl * 512 + w * 128;

  f32x4 acc[4][4];
  #pragma unroll
  for (int i = 0; i < 4; ++i)
    #pragma unroll
    for (int j = 0; j < 4; ++j) acc[i][j] = (f32x4){0.f, 0.f, 0.f, 0.f};
  float kpart[4] = {0.f, 0.f, 0.f, 0.f};

  #pragma unroll
  for (int kstep = 0; kstep < 4; ++kstep) {
    int tok = tk0 + kstep * 32 + kq * 8;
    bf16x8 af[4], bfr[4];
    #pragma unroll
    for (int mi = 0; mi < 4; ++mi)
      af[mi] = *(const bf16x8*)&vb[(size_t)(mi * 16 + frow) * 4096 + tok];
    #pragma unroll
    for (int ni = 0; ni < 4; ++ni) {
      bfr[ni] = *(const bf16x8*)&kb[(size_t)(ni * 16 + frow) * 4096 + tok];
      #pragma unroll
      for (int j = 0; j < 8; ++j) kpart[ni] += bf2f((ushort)bfr[ni][j]);
    }
    #pragma unroll
    for (int mi = 0; mi < 4; ++mi)
      #pragma unroll
      for (int ni = 0; ni < 4; ++ni)
        acc[mi][ni] = __builtin_amdgcn_mfma_f32_16x16x32_bf16(
            af[mi], bfr[ni], acc[mi][ni], 0, 0, 0);
  }

  // ksum: reduce kq groups, then one atomic per (d) per wave
  #pragma unroll
  for (int ni = 0; ni < 4; ++ni) {
    kpart[ni] += __shfl_xor(kpart[ni], 16);
    kpart[ni] += __shfl_xor(kpart[ni], 32);
  }
  if (lane < 16) {
    #pragma unroll
    for (int ni = 0; ni < 4; ++ni)
      atomicAdd(&ksum[(b * 16 + h) * 64 + ni * 16 + frow], kpart[ni]);
  }

  // cross-wave reduce acc, then atomicAdd to global kvT
  #pragma unroll
  for (int mi = 0; mi < 4; ++mi)
    #pragma unroll
    for (int ni = 0; ni < 4; ++ni)
      #pragma unroll
      for (int r = 0; r < 4; ++r)
        red[w][(mi * 16 + kq * 4 + r) * 64 + ni * 16 + frow] = acc[mi][ni][r];
  __syncthreads();
  float* kvg = kvT + (size_t)(b * 16 + h) * 4096;
  for (int i = tid; i < 4096; i += 256) {
    float s = red[0][i] + red[1][i] + red[2][i] + red[3][i];
    atomicAdd(&kvg[i], s);
  }
}

// ---------------- out[n,e] = z * sum_d q[n,d]*kvT[e,d]  (MFMA) ----------------
// grid 1024 = b(4) x h(16) x 256-token chunk(16); 4 waves x 64 tokens.
// kvT staged fp32->bf16 in LDS [64][72]; z-dot from A-frags + fp32 ksum.
__global__ __launch_bounds__(256)
void attn_out_mfma(const ushort* __restrict__ qb, const float* __restrict__ kvT,
                   const float* __restrict__ ksum, ushort* __restrict__ ao) {
  __shared__ ushort skv[64 * 72];
  __shared__ float sks[64];
  int bi = blockIdx.x;
  int c = bi & 15, h = (bi >> 4) & 15, b = bi >> 8;
  int tid = threadIdx.x, lane = tid & 63, w = tid >> 6;
  int frow = lane & 15, kq = lane >> 4;
  const float* kvg = kvT + (size_t)(b * 16 + h) * 4096;
  for (int i = tid; i < 4096; i += 256)
    skv[(i >> 6) * 72 + (i & 63)] = f2bf(kvg[i]);
  if (tid < 64) sks[tid] = ksum[(b * 16 + h) * 64 + tid];
  __syncthreads();

  int m0 = b * 4096 + c * 256 + w * 64;
  f32x4 acc[4][4];
  #pragma unroll
  for (int i = 0; i < 4; ++i)
    #pragma unroll
    for (int j = 0; j < 4; ++j) acc[i][j] = (f32x4){0.f, 0.f, 0.f, 0.f};
  float dp[4] = {0.f, 0.f, 0.f, 0.f};

  #pragma unroll
  for (int kst = 0; kst < 2; ++kst) {
    int d0 = kst * 32 + kq * 8;
    bf16x8 af[4], bfr[4];
    #pragma unroll
    for (int mi = 0; mi < 4; ++mi)
      af[mi] = *(const bf16x8*)&qb[(size_t)(m0 + mi * 16 + frow) * 1024 + h * 64 + d0];
    #pragma unroll
    for (int ni = 0; ni < 4; ++ni)
      bfr[ni] = *(const bf16x8*)&skv[(ni * 16 + frow) * 72 + d0];
    #pragma unroll
    for (int mi = 0; mi < 4; ++mi) {
      float s = 0.f;
      #pragma unroll
      for (int j = 0; j < 8; ++j) s += bf2f((ushort)af[mi][j]) * sks[d0 + j];
      dp[mi] += s;
    }
    #pragma unroll
    for (int mi = 0; mi < 4; ++mi)
      #pragma unroll
      for (int ni = 0; ni < 4; ++ni)
        acc[mi][ni] = __builtin_amdgcn_mfma_f32_16x16x32_bf16(
            af[mi], bfr[ni], acc[mi][ni], 0, 0, 0);
  }

  #pragma unroll
  for (int mi = 0; mi < 4; ++mi) {
    dp[mi] += __shfl_xor(dp[mi], 16);
    dp[mi] += __shfl_xor(dp[mi], 32);
  }

  #pragma unroll
  for (int mi = 0; mi < 4; ++mi)
    #pragma unroll
    for (int ni = 0; ni < 4; ++ni)
      #pragma unroll
      for (int r = 0; r < 4; ++r) {
        float dotv = __shfl(dp[mi], (kq << 2) + r);   // lane holding row kq*4+r
        float z = 1.f / (dotv + 1e-6f);
        int mrow = m0 + mi * 16 + kq * 4 + r;
        ao[(size_t)mrow * 1024 + h * 64 + ni * 16 + frow] =
            f2bf(acc[mi][ni][r] * z);
      }
}

extern "C" void kernel_launch(void* const* d_in, const int* in_sizes, int n_in,
                              void* d_out, int out_size, void* d_ws, size_t ws_size,
                              hipStream_t stream) {
  const float* x       = (const float*)d_in[0];
  const float* scale1  = (const float*)d_in[1];
  const float* scale2  = (const float*)d_in[2];
  const float* gamma   = (const float*)d_in[3];
  const float* qkv_w   = (const float*)d_in[4];
  const float* proj_w  = (const float*)d_in[5];
  const float* proj_b  = (const float*)d_in[6];
  const float* conv1_w = (const float*)d_in[7];
  const float* conv1_b = (const float*)d_in[8];
  const float* conv2_w = (const float*)d_in[9];
  const float* conv2_b = (const float*)d_in[10];
  float* out = (float*)d_out;

  char* ws = (char*)d_ws;
  size_t off = 0;
  auto alloc = [&](size_t bytes) {
    void* p = ws + off;
    off += (bytes + 255) & ~(size_t)255;
    return p;
  };
  ushort* xn     = (ushort*)alloc((size_t)MTOK * 1024 * 2);
  ushort* qb     = (ushort*)alloc((size_t)MTOK * 1024 * 2);
  ushort* kT     = (ushort*)alloc((size_t)MTOK * 1024 * 2);  // [b,h,d,n]
  ushort* vT     = (ushort*)alloc((size_t)MTOK * 1024 * 2);  // [b,h,e,n]; kT+vT reused as MLP hidden
  ushort* attn_o = (ushort*)alloc((size_t)MTOK * 1024 * 2);
  float*  kvT    = (float*)alloc((size_t)(4 * 16 * 64 * 64 + 4 * 16 * 64) * 4);
  float*  ksum   = kvT + 4 * 16 * 64 * 64;
  ushort* wq = (ushort*)alloc((size_t)3072 * 1024 * 2);
  ushort* wp = (ushort*)alloc((size_t)1024 * 1024 * 2);
  ushort* w1 = (ushort*)alloc((size_t)2048 * 1024 * 2);
  ushort* w2 = (ushort*)alloc((size_t)1024 * 2048 * 2);
  ushort* hid = kT;   // [MTOK][2048] bf16 == kT(32MB)+vT(32MB), dead after attention
  if (off > ws_size) return;

  hipMemsetAsync(kvT, 0, (size_t)(4 * 16 * 64 * 64 + 4 * 16 * 64) * 4, stream);
  f32_to_bf16_k<<<3072, 256, 0, stream>>>(qkv_w, wq, 786432);
  f32_to_bf16_k<<<1024, 256, 0, stream>>>(proj_w, wp, 262144);
  f32_to_bf16_k<<<2048, 256, 0, stream>>>(conv1_w, w1, 524288);
  f32_to_bf16_k<<<2048, 256, 0, stream>>>(conv2_w, w2, 524288);

  // attention branch
  rmsnorm_k<<<MTOK, 256, 0, stream>>>(x, scale1, xn);
  gemm_bt<0><<<128 * 24, 256, 0, stream>>>(xn, wq, qb, nullptr, nullptr, nullptr,
                                           kT, vT, MTOK, 3072, 1024);
  attn_kv_mfma<<<512, 256, 0, stream>>>(kT, vT, kvT, ksum);
  attn_out_mfma<<<1024, 256, 0, stream>>>(qb, kvT, ksum, attn_o);
  gemm_bt<1><<<128 * 8, 256, 0, stream>>>(attn_o, wp, out, proj_b, gamma, x,
                                          nullptr, nullptr, MTOK, 1024, 1024);

  // MLP branch (x1 lives in d_out; conv2 epilogue reads+rewrites it)
  rmsnorm_k<<<MTOK, 256, 0, stream>>>(out, scale2, xn);
  gemm_bt<2><<<128 * 16, 256, 0, stream>>>(xn, w1, hid, conv1_b, nullptr, nullptr,
                                           nullptr, nullptr, MTOK, 2048, 1024);
  gemm_bt<1><<<128 * 8, 256, 0, stream>>>(hid, w2, out, conv2_b, gamma, out,
                                          nullptr, nullptr, MTOK, 1024, 2048);
}